// Round 1
// baseline (376.515 us; speedup 1.0000x reference)
//
#include <hip/hip_runtime.h>
#include <math.h>

// Problem constants (fixed by the reference: N=10 features, P=6 parts)
#define NF 10
#define PP 6
#define HI 7776          // 6^5
#define HI4 1944         // 7776/4
#define BLK 256

// ws float layout: [0]=num accumulator, [1]=den, [8..8+7776)=W_hi, then W_lo

__global__ void tsk_prep(const float* __restrict__ X,
                         const float* __restrict__ a,
                         const float* __restrict__ b,
                         float* __restrict__ ws) {
    __shared__ float h[NF][PP];
    const int tid = threadIdx.x;
    if (tid < NF * PP) {
        const int k = tid / PP;
        const float d = a[tid] - X[k];
        const float bb = b[tid];
        h[k][tid % PP] = expf(-(d * d) / (2.0f * bb * bb));
    }
    __syncthreads();
    float* Whi = ws + 8;
    float* Wlo = Whi + HI;
    for (int r = tid; r < HI; r += blockDim.x) {
        int t = r;
        const int d4 = t % 6; t /= 6;
        const int d3 = t % 6; t /= 6;
        const int d2 = t % 6; t /= 6;
        const int d1 = t % 6; t /= 6;
        const int d0 = t;
        Whi[r] = h[0][d0] * h[1][d1] * h[2][d2] * h[3][d3] * h[4][d4];
        Wlo[r] = h[5][d0] * h[6][d1] * h[7][d2] * h[8][d3] * h[9][d4];
    }
    if (tid == 0) {
        float den = 1.0f;
        for (int k = 0; k < NF; ++k) {
            float s = 0.0f;
            for (int i = 0; i < PP; ++i) s += h[k][i];
            den *= s;
        }
        ws[0] = 0.0f;   // num accumulator (ws is poisoned 0xAA before every launch)
        ws[1] = den;
    }
}

__global__ __launch_bounds__(BLK) void tsk_dot(const float* __restrict__ y,
                                               float* __restrict__ ws) {
    const float* __restrict__ Whi = ws + 8;
    const float* __restrict__ Wlo = Whi + HI;
    const int r = blockIdx.x;                       // one 7776-elem row of y per block
    const float4* __restrict__ yrow = (const float4*)(y + (size_t)r * HI);
    const float4* __restrict__ wlo4 = (const float4*)Wlo;

    float acc = 0.0f;
    for (int c = threadIdx.x; c < HI4; c += BLK) {
        const float4 yv = yrow[c];
        const float4 wv = wlo4[c];                  // 31 KB table, L1/L2-resident
        acc += yv.x * wv.x + yv.y * wv.y + yv.z * wv.z + yv.w * wv.w;
    }
    acc *= Whi[r];

    // wave (64-lane) shuffle reduction, then cross-wave via LDS
    #pragma unroll
    for (int off = 32; off > 0; off >>= 1) acc += __shfl_down(acc, off, 64);
    __shared__ float ssum[BLK / 64];
    const int lane = threadIdx.x & 63;
    const int wave = threadIdx.x >> 6;
    if (lane == 0) ssum[wave] = acc;
    __syncthreads();
    if (threadIdx.x == 0) {
        float s = 0.0f;
        #pragma unroll
        for (int w = 0; w < BLK / 64; ++w) s += ssum[w];
        atomicAdd(ws, s);                           // device-scope by default on CDNA
    }
}

__global__ void tsk_finish(const float* __restrict__ ws, float* __restrict__ out) {
    out[0] = ws[0] / ws[1];
}

extern "C" void kernel_launch(void* const* d_in, const int* in_sizes, int n_in,
                              void* d_out, int out_size, void* d_ws, size_t ws_size,
                              hipStream_t stream) {
    const float* X = (const float*)d_in[0];   // [10]
    const float* a = (const float*)d_in[1];   // [10,6]
    const float* b = (const float*)d_in[2];   // [10,6]
    const float* y = (const float*)d_in[3];   // [6^9, 6] -> flat 6^10
    float* out = (float*)d_out;
    float* ws  = (float*)d_ws;                // needs (8 + 2*7776)*4 ≈ 62 KB

    tsk_prep<<<1, 1024, 0, stream>>>(X, a, b, ws);
    tsk_dot<<<HI, BLK, 0, stream>>>(y, ws);
    tsk_finish<<<1, 1, 0, stream>>>(ws, out);
}

// Round 3
// 314.871 us; speedup vs baseline: 1.1958x; 1.1958x over previous
//
#include <hip/hip_runtime.h>
#include <math.h>

// Zero-order TSK: out = (Whi . Y . Wlo) / prod_k(sum_i h[k][i])
// where Y is y reshaped [7776, 7776], Whi/Wlo are 5-feature membership
// outer products. Only y (242 MB) must stream from HBM -> memory-bound,
// floor ~38 us at 6.3 TB/s achievable.

#define NF 10
#define PP 6
#define HI 7776          // 6^5
#define HI4 1944         // 7776/4 float4s per row
#define BLK 256

typedef float fvec4 __attribute__((ext_vector_type(4)));  // clang-native: ok for nontemporal builtin

// ws float layout:
//   [0] = den
//   [8 .. 8+7776)           = W_hi
//   [7784 .. 7784+7776)     = W_lo      (offset 7784*4 B, 16B-aligned)
//   [15560 .. 15560+7776)   = partial[r]

__global__ void tsk_prep(const float* __restrict__ X,
                         const float* __restrict__ a,
                         const float* __restrict__ b,
                         float* __restrict__ ws) {
    __shared__ float h[NF][PP];
    const int tid = threadIdx.x;
    if (tid < NF * PP) {
        const int k = tid / PP;
        const float d = a[tid] - X[k];
        const float bb = b[tid];
        h[k][tid % PP] = expf(-(d * d) / (2.0f * bb * bb));
    }
    __syncthreads();
    float* __restrict__ Whi = ws + 8;
    float* __restrict__ Wlo = ws + 8 + HI;
    for (int r = tid; r < HI; r += blockDim.x) {
        int t = r;
        const int d4 = t % 6; t /= 6;
        const int d3 = t % 6; t /= 6;
        const int d2 = t % 6; t /= 6;
        const int d1 = t % 6; t /= 6;
        const int d0 = t;
        Whi[r] = h[0][d0] * h[1][d1] * h[2][d2] * h[3][d3] * h[4][d4];
        Wlo[r] = h[5][d0] * h[6][d1] * h[7][d2] * h[8][d3] * h[9][d4];
    }
    if (tid == 0) {
        float den = 1.0f;
        for (int k = 0; k < NF; ++k) {
            float s = 0.0f;
            for (int i = 0; i < PP; ++i) s += h[k][i];
            den *= s;
        }
        ws[0] = den;
    }
}

__global__ __launch_bounds__(BLK) void tsk_dot(const float* __restrict__ y,
                                               float* __restrict__ ws) {
    const fvec4* __restrict__ wlo4 = (const fvec4*)(ws + 8 + HI);
    float* __restrict__ partial = ws + 8 + 2 * HI;
    const int r = blockIdx.x;                       // one 7776-elem row of Y
    const fvec4* __restrict__ yrow = (const fvec4*)(y + (size_t)r * HI);
    const int t = threadIdx.x;

    float acc = 0.0f;
    // 1944 = 7*256 + 152: compile-time unroll -> 8 independent load pairs in flight
    #pragma unroll
    for (int k = 0; k < 7; ++k) {
        const int c = t + k * BLK;
        const fvec4 yv = __builtin_nontemporal_load(yrow + c);   // y: zero reuse
        const fvec4 wv = wlo4[c];                                 // 31 KB, L1/L2-hot
        acc += yv.x * wv.x + yv.y * wv.y + yv.z * wv.z + yv.w * wv.w;
    }
    {
        const int c = t + 7 * BLK;
        if (c < HI4) {
            const fvec4 yv = __builtin_nontemporal_load(yrow + c);
            const fvec4 wv = wlo4[c];
            acc += yv.x * wv.x + yv.y * wv.y + yv.z * wv.z + yv.w * wv.w;
        }
    }

    // wave(64) shuffle reduce, then cross-wave via LDS
    #pragma unroll
    for (int off = 32; off > 0; off >>= 1) acc += __shfl_down(acc, off, 64);
    __shared__ float ssum[BLK / 64];
    const int lane = t & 63;
    const int wave = t >> 6;
    if (lane == 0) ssum[wave] = acc;
    __syncthreads();
    if (t == 0) {
        float s = 0.0f;
        #pragma unroll
        for (int w = 0; w < BLK / 64; ++w) s += ssum[w];
        partial[r] = s;                 // distinct address per block: no contention
    }
}

__global__ __launch_bounds__(1024) void tsk_reduce(const float* __restrict__ ws,
                                                   float* __restrict__ out) {
    const float* __restrict__ Whi = ws + 8;
    const float* __restrict__ partial = ws + 8 + 2 * HI;
    const int t = threadIdx.x;

    float acc = 0.0f;
    #pragma unroll
    for (int k = 0; k < 8; ++k) {       // 8*1024 >= 7776
        const int r = t + k * 1024;
        if (r < HI) acc += partial[r] * Whi[r];
    }
    #pragma unroll
    for (int off = 32; off > 0; off >>= 1) acc += __shfl_down(acc, off, 64);
    __shared__ float ssum[16];
    const int lane = t & 63;
    const int wave = t >> 6;
    if (lane == 0) ssum[wave] = acc;
    __syncthreads();
    if (t == 0) {
        float s = 0.0f;
        #pragma unroll
        for (int w = 0; w < 16; ++w) s += ssum[w];
        out[0] = s / ws[0];
    }
}

extern "C" void kernel_launch(void* const* d_in, const int* in_sizes, int n_in,
                              void* d_out, int out_size, void* d_ws, size_t ws_size,
                              hipStream_t stream) {
    const float* X = (const float*)d_in[0];   // [10]
    const float* a = (const float*)d_in[1];   // [10,6]
    const float* b = (const float*)d_in[2];   // [10,6]
    const float* y = (const float*)d_in[3];   // flat 6^10
    float* out = (float*)d_out;
    float* ws  = (float*)d_ws;                // uses ~93 KB

    tsk_prep<<<1, 1024, 0, stream>>>(X, a, b, ws);
    tsk_dot<<<HI, BLK, 0, stream>>>(y, ws);
    tsk_reduce<<<1, 1024, 0, stream>>>(ws, out);
}

// Round 4
// 312.345 us; speedup vs baseline: 1.2054x; 1.0081x over previous
//
#include <hip/hip_runtime.h>
#include <math.h>

// Zero-order TSK: out = (Whi . Y . Wlo) / prod_k(sum_i h[k][i]),
// Y = y reshaped [7776, 7776]; Whi/Wlo are 5-feature membership outer
// products (each 7776 entries, rebuilt per block in LDS for ~free).
// Only y (242 MB) streams from HBM -> memory-bound, floor ~40 us.

#define NF 10
#define PP 6
#define HI 7776          // 6^5
#define HI4 1944         // 7776/4 float4s per row = 7*256 + 152
#define BLK 256
#define ROWS 2           // rows of Y per block; grid = 7776/ROWS = 3888

typedef float fvec4 __attribute__((ext_vector_type(4)));

// ws float layout: [0..7776) = partial[r] (includes Whi factor)

__device__ __forceinline__ float memb(const float* X, const float* a,
                                      const float* b, int idx) {
    const int k = idx / PP;
    const float d = a[idx] - X[k];
    const float bb = b[idx];
    return __expf(-(d * d) / (2.0f * bb * bb));
}

__global__ __launch_bounds__(BLK) void tsk_fused(const float* __restrict__ X,
                                                 const float* __restrict__ a,
                                                 const float* __restrict__ b,
                                                 const float* __restrict__ y,
                                                 float* __restrict__ ws) {
    __shared__ float h[NF][PP];
    __shared__ float wlo[HI];            // 31104 B
    __shared__ float ssum[BLK / 64][ROWS];
    const int t = threadIdx.x;

    if (t < NF * PP) h[t / PP][t % PP] = memb(X, a, b, t);
    __syncthreads();

    // Build W_lo (features 5..9) in LDS: ~30 iters/thread, VALU-cheap,
    // hidden under the other resident blocks' y streams.
    for (int c = t; c < HI; c += BLK) {
        int u = c;
        const int d9 = u % 6; u /= 6;
        const int d8 = u % 6; u /= 6;
        const int d7 = u % 6; u /= 6;
        const int d6 = u % 6; u /= 6;
        const int d5 = u;
        wlo[c] = h[5][d5] * h[6][d6] * h[7][d7] * h[8][d8] * h[9][d9];
    }
    __syncthreads();

    const fvec4* __restrict__ wlo4 = (const fvec4*)wlo;
    const int r0 = blockIdx.x * ROWS;

    // Dot each row against LDS W_lo; NO barrier between rows so the
    // global load stream never drains.
    float accs[ROWS];
    for (int i = 0; i < ROWS; ++i) {
        const fvec4* __restrict__ yrow = (const fvec4*)(y + (size_t)(r0 + i) * HI);
        float acc = 0.0f;
        #pragma unroll
        for (int k = 0; k < 7; ++k) {
            const int c = t + k * BLK;
            const fvec4 yv = __builtin_nontemporal_load(yrow + c);  // zero reuse
            const fvec4 wv = wlo4[c];                                // LDS
            acc += yv.x * wv.x + yv.y * wv.y + yv.z * wv.z + yv.w * wv.w;
        }
        const int c = t + 7 * BLK;
        if (c < HI4) {
            const fvec4 yv = __builtin_nontemporal_load(yrow + c);
            const fvec4 wv = wlo4[c];
            acc += yv.x * wv.x + yv.y * wv.y + yv.z * wv.z + yv.w * wv.w;
        }
        accs[i] = acc;
    }

    // Single deferred reduction phase for all rows.
    #pragma unroll
    for (int i = 0; i < ROWS; ++i) {
        #pragma unroll
        for (int off = 32; off > 0; off >>= 1)
            accs[i] += __shfl_down(accs[i], off, 64);
    }
    const int lane = t & 63;
    const int wave = t >> 6;
    if (lane == 0) {
        #pragma unroll
        for (int i = 0; i < ROWS; ++i) ssum[wave][i] = accs[i];
    }
    __syncthreads();
    if (t < ROWS) {                       // thread i finalizes row r0+i
        float s = 0.0f;
        #pragma unroll
        for (int w = 0; w < BLK / 64; ++w) s += ssum[w][t];
        int u = r0 + t;
        const int d4 = u % 6; u /= 6;
        const int d3 = u % 6; u /= 6;
        const int d2 = u % 6; u /= 6;
        const int d1 = u % 6; u /= 6;
        const int d0 = u;
        const float whi = h[0][d0] * h[1][d1] * h[2][d2] * h[3][d3] * h[4][d4];
        ws[r0 + t] = s * whi;             // partial[r], distinct addresses
    }
}

__global__ __launch_bounds__(1024) void tsk_reduce(const float* __restrict__ X,
                                                   const float* __restrict__ a,
                                                   const float* __restrict__ b,
                                                   const float* __restrict__ ws,
                                                   float* __restrict__ out) {
    __shared__ float h[NF * PP];
    __shared__ float ssum[16];
    const int t = threadIdx.x;
    if (t < NF * PP) h[t] = memb(X, a, b, t);

    float acc = 0.0f;
    #pragma unroll
    for (int k = 0; k < 8; ++k) {        // 8*1024 >= 7776
        const int r = t + k * 1024;
        if (r < HI) acc += ws[r];
    }
    #pragma unroll
    for (int off = 32; off > 0; off >>= 1) acc += __shfl_down(acc, off, 64);
    const int lane = t & 63;
    const int wave = t >> 6;
    if (lane == 0) ssum[wave] = acc;
    __syncthreads();
    if (t == 0) {
        float num = 0.0f;
        #pragma unroll
        for (int w = 0; w < 16; ++w) num += ssum[w];
        float den = 1.0f;
        for (int k = 0; k < NF; ++k) {
            float s = 0.0f;
            for (int i = 0; i < PP; ++i) s += h[k * PP + i];
            den *= s;
        }
        out[0] = num / den;
    }
}

extern "C" void kernel_launch(void* const* d_in, const int* in_sizes, int n_in,
                              void* d_out, int out_size, void* d_ws, size_t ws_size,
                              hipStream_t stream) {
    const float* X = (const float*)d_in[0];   // [10]
    const float* a = (const float*)d_in[1];   // [10,6]
    const float* b = (const float*)d_in[2];   // [10,6]
    const float* y = (const float*)d_in[3];   // flat 6^10
    float* out = (float*)d_out;
    float* ws  = (float*)d_ws;                // uses 31 KB

    tsk_fused<<<HI / ROWS, BLK, 0, stream>>>(X, a, b, y, ws);
    tsk_reduce<<<1, 1024, 0, stream>>>(X, a, b, ws, out);
}

// Round 5
// 311.256 us; speedup vs baseline: 1.2097x; 1.0035x over previous
//
#include <hip/hip_runtime.h>
#include <math.h>

// Zero-order TSK: out = (Whi . Y . Wlo) / prod_k(sum_i h[k][i]),
// Y = y reshaped [7776, 7776]; Whi/Wlo are 5-feature membership outer
// products. Wlo (7776 floats) is built per-block in LDS via a staged
// outer-product chain (6->36->216->1296->7776, ~6 ops/elem). Only y
// (242 MB) streams from HBM -> memory-bound, floor ~40 us.

#define NF 10
#define PP 6
#define HI 7776          // 6^5
#define HI4 1944         // 7776/4 float4s per row = 7*256 + 152
#define BLK 256
#define ROWS 4           // rows of Y per block; grid = 7776/4 = 1944

typedef float fvec4 __attribute__((ext_vector_type(4)));

// ws float layout: [0..7776) = partial[r] (includes Whi factor)

__device__ __forceinline__ float memb(const float* X, const float* a,
                                      const float* b, int idx) {
    const int k = idx / PP;
    const float d = a[idx] - X[k];
    const float bb = b[idx];
    return __expf(-(d * d) / (2.0f * bb * bb));
}

__global__ __launch_bounds__(BLK) void tsk_fused(const float* __restrict__ X,
                                                 const float* __restrict__ a,
                                                 const float* __restrict__ b,
                                                 const float* __restrict__ y,
                                                 float* __restrict__ ws) {
    __shared__ float h[NF][PP];
    __shared__ float wlo[HI];            // 31104 B
    __shared__ float scr[1296 + 216];    // staged-build scratch: A=scr[0..1296), B=scr[1296..)
    __shared__ float ssum[BLK / 64][ROWS];
    const int t = threadIdx.x;
    float* __restrict__ A = scr;
    float* __restrict__ B = scr + 1296;

    if (t < NF * PP) h[t / PP][t % PP] = memb(X, a, b, t);
    __syncthreads();

    // Staged outer-product build of W_lo (features 5..9), MSB digit = feature 5.
    if (t < 36)  A[t] = h[5][t / 6] * h[6][t % 6];            // t36
    __syncthreads();
    if (t < 216) B[t] = A[t / 6] * h[7][t % 6];               // t216
    __syncthreads();
    for (int c = t; c < 1296; c += BLK) A[c] = B[c / 6] * h[8][c % 6];  // t1296 (overwrites t36, dead)
    __syncthreads();
    for (int c = t; c < HI; c += BLK)  wlo[c] = A[c / 6] * h[9][c % 6];
    __syncthreads();

    const fvec4* __restrict__ wlo4 = (const fvec4*)wlo;
    const int r0 = blockIdx.x * ROWS;
    const fvec4* __restrict__ yr0 = (const fvec4*)(y + (size_t)(r0 + 0) * HI);
    const fvec4* __restrict__ yr1 = (const fvec4*)(y + (size_t)(r0 + 1) * HI);
    const fvec4* __restrict__ yr2 = (const fvec4*)(y + (size_t)(r0 + 2) * HI);
    const fvec4* __restrict__ yr3 = (const fvec4*)(y + (size_t)(r0 + 3) * HI);

    // 4 independent global streams per lane; one LDS read of wv serves 4 rows.
    float acc0 = 0.f, acc1 = 0.f, acc2 = 0.f, acc3 = 0.f;
    #pragma unroll
    for (int k = 0; k < 7; ++k) {
        const int c = t + k * BLK;
        const fvec4 wv = wlo4[c];
        const fvec4 y0 = __builtin_nontemporal_load(yr0 + c);
        const fvec4 y1 = __builtin_nontemporal_load(yr1 + c);
        const fvec4 y2 = __builtin_nontemporal_load(yr2 + c);
        const fvec4 y3 = __builtin_nontemporal_load(yr3 + c);
        acc0 += y0.x * wv.x + y0.y * wv.y + y0.z * wv.z + y0.w * wv.w;
        acc1 += y1.x * wv.x + y1.y * wv.y + y1.z * wv.z + y1.w * wv.w;
        acc2 += y2.x * wv.x + y2.y * wv.y + y2.z * wv.z + y2.w * wv.w;
        acc3 += y3.x * wv.x + y3.y * wv.y + y3.z * wv.z + y3.w * wv.w;
    }
    {
        const int c = t + 7 * BLK;
        if (c < HI4) {
            const fvec4 wv = wlo4[c];
            const fvec4 y0 = __builtin_nontemporal_load(yr0 + c);
            const fvec4 y1 = __builtin_nontemporal_load(yr1 + c);
            const fvec4 y2 = __builtin_nontemporal_load(yr2 + c);
            const fvec4 y3 = __builtin_nontemporal_load(yr3 + c);
            acc0 += y0.x * wv.x + y0.y * wv.y + y0.z * wv.z + y0.w * wv.w;
            acc1 += y1.x * wv.x + y1.y * wv.y + y1.z * wv.z + y1.w * wv.w;
            acc2 += y2.x * wv.x + y2.y * wv.y + y2.z * wv.z + y2.w * wv.w;
            acc3 += y3.x * wv.x + y3.y * wv.y + y3.z * wv.z + y3.w * wv.w;
        }
    }

    // wave(64) shuffle reduce all rows, then cross-wave via LDS.
    #pragma unroll
    for (int off = 32; off > 0; off >>= 1) {
        acc0 += __shfl_down(acc0, off, 64);
        acc1 += __shfl_down(acc1, off, 64);
        acc2 += __shfl_down(acc2, off, 64);
        acc3 += __shfl_down(acc3, off, 64);
    }
    const int lane = t & 63;
    const int wave = t >> 6;
    if (lane == 0) {
        ssum[wave][0] = acc0; ssum[wave][1] = acc1;
        ssum[wave][2] = acc2; ssum[wave][3] = acc3;
    }
    __syncthreads();
    if (t < ROWS) {                       // thread i finalizes row r0+i
        float s = 0.0f;
        #pragma unroll
        for (int w = 0; w < BLK / 64; ++w) s += ssum[w][t];
        int u = r0 + t;
        const int d4 = u % 6; u /= 6;
        const int d3 = u % 6; u /= 6;
        const int d2 = u % 6; u /= 6;
        const int d1 = u % 6; u /= 6;
        const int d0 = u;
        const float whi = h[0][d0] * h[1][d1] * h[2][d2] * h[3][d3] * h[4][d4];
        ws[r0 + t] = s * whi;             // distinct addresses, no contention
    }
}

__global__ __launch_bounds__(1024) void tsk_reduce(const float* __restrict__ X,
                                                   const float* __restrict__ a,
                                                   const float* __restrict__ b,
                                                   const float* __restrict__ ws,
                                                   float* __restrict__ out) {
    __shared__ float h[NF * PP];
    __shared__ float ssum[16];
    const int t = threadIdx.x;
    if (t < NF * PP) h[t] = memb(X, a, b, t);

    float acc = 0.0f;
    #pragma unroll
    for (int k = 0; k < 8; ++k) {        // 8*1024 >= 7776
        const int r = t + k * 1024;
        if (r < HI) acc += ws[r];
    }
    #pragma unroll
    for (int off = 32; off > 0; off >>= 1) acc += __shfl_down(acc, off, 64);
    const int lane = t & 63;
    const int wave = t >> 6;
    if (lane == 0) ssum[wave] = acc;
    __syncthreads();
    if (t == 0) {
        float num = 0.0f;
        #pragma unroll
        for (int w = 0; w < 16; ++w) num += ssum[w];
        float den = 1.0f;
        for (int k = 0; k < NF; ++k) {
            float s = 0.0f;
            for (int i = 0; i < PP; ++i) s += h[k * PP + i];
            den *= s;
        }
        out[0] = num / den;
    }
}

extern "C" void kernel_launch(void* const* d_in, const int* in_sizes, int n_in,
                              void* d_out, int out_size, void* d_ws, size_t ws_size,
                              hipStream_t stream) {
    const float* X = (const float*)d_in[0];   // [10]
    const float* a = (const float*)d_in[1];   // [10,6]
    const float* b = (const float*)d_in[2];   // [10,6]
    const float* y = (const float*)d_in[3];   // flat 6^10
    float* out = (float*)d_out;
    float* ws  = (float*)d_ws;                // uses 31 KB

    tsk_fused<<<HI / ROWS, BLK, 0, stream>>>(X, a, b, y, ws);
    tsk_reduce<<<1, 1024, 0, stream>>>(X, a, b, ws, out);
}